// Round 11
// baseline (192.862 us; speedup 1.0000x reference)
//
#include <hip/hip_runtime.h>

// DeformableConvNet v4.1 — K-split 4-wave blocks + XCD-aligned swizzle.
// R7: deform_mfma latency/locality-bound: occupancy 19.7% (2 waves/SIMD),
// FETCH 188MB (5-row windows refetched across XCDs), HBM 2.6TB/s.
// v4: 2048 blocks (strip=32px, 4 c-quarter waves, LDS K-reduce) -> 16
// waves/CU; XCD swizzle gives each XCD a contiguous 64-row window (~2.9MB
// < 4MB L2), consistent across xpose/offconv/deform.
// v4.1 fixes v4's LDS race: staging region now disjoint from reduce bufs
// (bufA[0,2048) bufB[2048,4096) staging[4096,6208)).

#define HWSZ 16384  // 128*128
#define CIN  64
#define OUTC 64

typedef __attribute__((ext_vector_type(8))) short short8v;
typedef __attribute__((ext_vector_type(16))) float f32x16;

static __device__ __forceinline__ unsigned bf16rne(float f) {
    unsigned u = __float_as_uint(f);
    return (u + 0x7FFFu + ((u >> 16) & 1u)) >> 16;
}

// ---------------- prep: wofT transpose + wB fragment packing ----------------
__global__ __launch_bounds__(256) void prep_kernel(const float* __restrict__ w_off,
                                                   const float* __restrict__ w_def,
                                                   float* __restrict__ ws) {
    int i = blockIdx.x * 256 + threadIdx.x;
    if (i < 10368) {
        int cj = i / 18, ch = i % 18;
        ws[i] = w_off[ch * 576 + cj];
    }
    // wB frag pack: i = ((s*2+ot)*2+hl)*512 + lane*8 + j ; s=kk*4+cq ;
    // c = cq*16+hf*8+j ; o = ot*32+(lane&31) ; hl 0=hi,1=lo residual.
    if (i < 73728) {
        unsigned short* wB = (unsigned short*)(ws + 16384);
        int j  = i & 7;
        int ln = (i >> 3) & 63;
        int hl = (i >> 9) & 1;
        int ot = (i >> 10) & 1;
        int s  = i >> 11;
        int kk = s >> 2, cq = s & 3;
        int hf = ln >> 5, r = ln & 31;
        int c  = cq * 16 + hf * 8 + j;
        int o  = ot * 32 + r;
        float wv = w_def[o * 576 + c * 9 + kk];
        unsigned hb = bf16rne(wv);
        if (hl == 0) {
            wB[i] = (unsigned short)hb;
        } else {
            float lo = wv - __uint_as_float(hb << 16);
            wB[i] = (unsigned short)bf16rne(lo);
        }
    }
}

// ---------------- transpose x: NCHW -> NHWC (XCD-swizzled rows) ----------------
__global__ __launch_bounds__(256) void xpose_kernel(const float* __restrict__ x,
                                                    float* __restrict__ xT) {
    __shared__ float lds[64 * 129];
    const int fid = blockIdx.x;            // 512
    const int xcd = fid & 7, j = fid >> 3; // j 0..63
    const int g = xcd * 64 + j;            // global row 0..511
    const int n = g >> 7, h = g & 127;
    const int t = threadIdx.x;
    for (int i = t; i < 8192; i += 256) {
        int c = i >> 7, w = i & 127;
        lds[c * 129 + w] = x[((size_t)(n * 64 + c) * 128 + h) * 128 + w];
    }
    __syncthreads();
    for (int i = t; i < 8192; i += 256) {
        int w = i >> 6, c = i & 63;
        xT[((size_t)(n * 128 + h) * 128 + w) * 64 + c] = lds[c * 129 + w];
    }
}

// ---------------- offset conv (NHWC in, (n,h,w,20) out), XCD-swizzled ----------------
__global__ __launch_bounds__(256) void offconv2_kernel(const float* __restrict__ xT,
                                                       const float* __restrict__ wofT,
                                                       const float* __restrict__ b_off,
                                                       float* __restrict__ off) {
    __shared__ float ldsA[64 * 19];
    __shared__ float ldsB[64 * 19];
    const int t = threadIdx.x;
    const int p = t & 63;
    const int cq = __builtin_amdgcn_readfirstlane(t >> 6);
    const int fid = blockIdx.x;            // 1024
    const int xcd = fid & 7, j = fid >> 3; // j 0..127
    const int gr = xcd * 16 + (j >> 3);    // global 4-row tile 0..127
    const int xt = j & 7;
    const int n = gr >> 5;
    const int h = (gr & 31) * 4 + (p >> 4);
    const int w = xt * 16 + (p & 15);

    float acc[18];
#pragma unroll
    for (int ch = 0; ch < 18; ++ch) acc[ch] = 0.f;

    const float* xb = xT + (size_t)n * (HWSZ * 64) + cq * 16;

#pragma unroll 1
    for (int jy = 0; jy < 3; ++jy) {
#pragma unroll 1
        for (int jx = 0; jx < 3; ++jx) {
            int hy = h + jy - 1, wx = w + jx - 1;
            bool v = (hy >= 0) && (hy < 128) && (wx >= 0) && (wx < 128);
            int hc = min(max(hy, 0), 127), wc = min(max(wx, 0), 127);
            float m = v ? 1.f : 0.f;
            const float* src = xb + (hc * 128 + wc) * 64;
            float4 v0 = *(const float4*)(src);
            float4 v1 = *(const float4*)(src + 4);
            float4 v2 = *(const float4*)(src + 8);
            float4 v3 = *(const float4*)(src + 12);
            float xv[16] = {v0.x, v0.y, v0.z, v0.w, v1.x, v1.y, v1.z, v1.w,
                            v2.x, v2.y, v2.z, v2.w, v3.x, v3.y, v3.z, v3.w};
            const float* wr0 = wofT + ((cq * 16) * 9 + (jy * 3 + jx)) * 18;
#pragma unroll
            for (int ci = 0; ci < 16; ++ci) {
                float s = xv[ci] * m;
                const float* wr = wr0 + ci * 162;
#pragma unroll
                for (int ch = 0; ch < 18; ++ch)
                    acc[ch] = fmaf(s, wr[ch], acc[ch]);
            }
        }
    }

    if (cq == 2) {
#pragma unroll
        for (int ch = 0; ch < 18; ++ch) ldsA[p * 19 + ch] = acc[ch];
    } else if (cq == 3) {
#pragma unroll
        for (int ch = 0; ch < 18; ++ch) ldsB[p * 19 + ch] = acc[ch];
    }
    __syncthreads();
    if (cq == 0) {
#pragma unroll
        for (int ch = 0; ch < 18; ++ch) acc[ch] += ldsA[p * 19 + ch];
    } else if (cq == 1) {
#pragma unroll
        for (int ch = 0; ch < 18; ++ch) acc[ch] += ldsB[p * 19 + ch];
    }
    __syncthreads();
    if (cq == 1) {
#pragma unroll
        for (int ch = 0; ch < 18; ++ch) ldsA[p * 19 + ch] = acc[ch];
    }
    __syncthreads();
    if (cq == 0) {
        float* op = off + ((size_t)(n * 128 + h) * 128 + w) * 20;
#pragma unroll
        for (int ch = 0; ch < 18; ++ch)
            op[ch] = acc[ch] + ldsA[p * 19 + ch] + b_off[ch];
    }
}

// ---------------- deformable conv v4.1: K-split 4-wave blocks ----------------
__global__ __launch_bounds__(256, 4) void deform_mfma4_kernel(
    const float* __restrict__ xT, const float* __restrict__ off20,
    const unsigned short* __restrict__ wB, const float* __restrict__ b_def,
    float* __restrict__ out) {
    // bufA [0,2048) | bufB [2048,4096) | staging [4096, 4096+32*66=6208)
    __shared__ float lds[6208];
    const int t = threadIdx.x;
    const int lane = t & 63;
    const int cq = __builtin_amdgcn_readfirstlane(t >> 6);  // wave's c-quarter
    const int r = lane & 31;     // A row = px-in-strip ; C col = o-in-tile
    const int hf = lane >> 5;    // k-half within 16-wide K step
    const int fid = blockIdx.x;            // 2048
    const int xcd = fid & 7, j = fid >> 3; // j 0..255
    const int g = xcd * 64 + (j >> 2);     // global row 0..511
    const int n = g >> 7, h = g & 127;
    const int w0 = (j & 3) * 32;
    const int w = w0 + r;

    f32x16 acc0, acc1;
#pragma unroll
    for (int i = 0; i < 16; ++i) { acc0[i] = 0.f; acc1[i] = 0.f; }

    const float* xb = xT + (size_t)n * (HWSZ * 64);
    const float* ob = off20 + ((size_t)(n * 128 + h) * 128 + w) * 20;
    const short8v* wb8 = (const short8v*)wB;
    const int c0 = cq * 16 + hf * 8;  // this lane's channel base

#pragma unroll 1
    for (int ky = 0; ky < 3; ++ky) {
#pragma unroll 1
        for (int kx = 0; kx < 3; ++kx) {
            const int kk = ky * 3 + kx;
            float2 d = *(const float2*)(ob + 2 * kk);
            float py  = (float)(h + ky - 1) + d.x;
            float pxx = (float)(w + kx - 1) + d.y;
            float y0f = floorf(py), x0f = floorf(pxx);
            float wy = py - y0f, wxf = pxx - x0f;
            int y0 = (int)y0f, x0 = (int)x0f;
            int y1 = y0 + 1, x1 = x0 + 1;
            bool vy0 = (y0 >= 0) && (y0 < 128), vy1 = (y1 >= 0) && (y1 < 128);
            bool vx0 = (x0 >= 0) && (x0 < 128), vx1 = (x1 >= 0) && (x1 < 128);
            int cy0 = min(max(y0, 0), 127), cy1 = min(max(y1, 0), 127);
            int cx0 = min(max(x0, 0), 127), cx1 = min(max(x1, 0), 127);
            float c00 = (vy0 && vx0) ? (1.f - wy) * (1.f - wxf) : 0.f;
            float c01 = (vy0 && vx1) ? (1.f - wy) * wxf : 0.f;
            float c10 = (vy1 && vx0) ? wy * (1.f - wxf) : 0.f;
            float c11 = (vy1 && vx1) ? wy * wxf : 0.f;

            const int s = kk * 4 + cq;
            short8v Bh0 = wb8[(s * 4 + 0) * 64 + lane];
            short8v Bl0 = wb8[(s * 4 + 1) * 64 + lane];
            short8v Bh1 = wb8[(s * 4 + 2) * 64 + lane];
            short8v Bl1 = wb8[(s * 4 + 3) * 64 + lane];

            const float* p00 = xb + (cy0 * 128 + cx0) * 64 + c0;
            const float* p01 = xb + (cy0 * 128 + cx1) * 64 + c0;
            const float* p10 = xb + (cy1 * 128 + cx0) * 64 + c0;
            const float* p11 = xb + (cy1 * 128 + cx1) * 64 + c0;
            float4 a0 = *(const float4*)(p00);
            float4 a1 = *(const float4*)(p00 + 4);
            float4 b0 = *(const float4*)(p01);
            float4 b1 = *(const float4*)(p01 + 4);
            float4 g0 = *(const float4*)(p10);
            float4 g1 = *(const float4*)(p10 + 4);
            float4 e0 = *(const float4*)(p11);
            float4 e1 = *(const float4*)(p11 + 4);
            float smp[8];
            smp[0] = c00 * a0.x + c01 * b0.x + c10 * g0.x + c11 * e0.x;
            smp[1] = c00 * a0.y + c01 * b0.y + c10 * g0.y + c11 * e0.y;
            smp[2] = c00 * a0.z + c01 * b0.z + c10 * g0.z + c11 * e0.z;
            smp[3] = c00 * a0.w + c01 * b0.w + c10 * g0.w + c11 * e0.w;
            smp[4] = c00 * a1.x + c01 * b1.x + c10 * g1.x + c11 * e1.x;
            smp[5] = c00 * a1.y + c01 * b1.y + c10 * g1.y + c11 * e1.y;
            smp[6] = c00 * a1.z + c01 * b1.z + c10 * g1.z + c11 * e1.z;
            smp[7] = c00 * a1.w + c01 * b1.w + c10 * g1.w + c11 * e1.w;
            short8v Ah, Al;
#pragma unroll
            for (int j2 = 0; j2 < 8; ++j2) {
                unsigned hb = bf16rne(smp[j2]);
                Ah[j2] = (short)hb;
                float lo = smp[j2] - __uint_as_float(hb << 16);
                Al[j2] = (short)bf16rne(lo);
            }
            acc0 = __builtin_amdgcn_mfma_f32_32x32x16_bf16(Ah, Bh0, acc0, 0, 0, 0);
            acc0 = __builtin_amdgcn_mfma_f32_32x32x16_bf16(Al, Bh0, acc0, 0, 0, 0);
            acc0 = __builtin_amdgcn_mfma_f32_32x32x16_bf16(Ah, Bl0, acc0, 0, 0, 0);
            acc1 = __builtin_amdgcn_mfma_f32_32x32x16_bf16(Ah, Bh1, acc1, 0, 0, 0);
            acc1 = __builtin_amdgcn_mfma_f32_32x32x16_bf16(Al, Bh1, acc1, 0, 0, 0);
            acc1 = __builtin_amdgcn_mfma_f32_32x32x16_bf16(Ah, Bl1, acc1, 0, 0, 0);
        }
    }

    // 4-way K-reduction: w2->bufA, w3->bufB; w0+=A, w1+=B; w1->bufA; w0+=A+bias.
    if (cq == 2) {
#pragma unroll
        for (int reg = 0; reg < 16; ++reg) {
            lds[reg * 64 + lane] = acc0[reg];
            lds[1024 + reg * 64 + lane] = acc1[reg];
        }
    } else if (cq == 3) {
#pragma unroll
        for (int reg = 0; reg < 16; ++reg) {
            lds[2048 + reg * 64 + lane] = acc0[reg];
            lds[3072 + reg * 64 + lane] = acc1[reg];
        }
    }
    __syncthreads();
    if (cq == 0) {
#pragma unroll
        for (int reg = 0; reg < 16; ++reg) {
            acc0[reg] += lds[reg * 64 + lane];
            acc1[reg] += lds[1024 + reg * 64 + lane];
        }
    } else if (cq == 1) {
#pragma unroll
        for (int reg = 0; reg < 16; ++reg) {
            acc0[reg] += lds[2048 + reg * 64 + lane];
            acc1[reg] += lds[3072 + reg * 64 + lane];
        }
    }
    __syncthreads();
    if (cq == 1) {
#pragma unroll
        for (int reg = 0; reg < 16; ++reg) {
            lds[reg * 64 + lane] = acc0[reg];
            lds[1024 + reg * 64 + lane] = acc1[reg];
        }
    }
    __syncthreads();
    if (cq == 0) {
        // final sum + bias -> staging [32px][66] at lds+4096 (disjoint from bufA)
#pragma unroll
        for (int reg = 0; reg < 16; ++reg) {
            float v0 = acc0[reg] + lds[reg * 64 + lane];
            float v1 = acc1[reg] + lds[1024 + reg * 64 + lane];
            int px = (reg & 3) + 8 * (reg >> 2) + 4 * hf;
            lds[4096 + px * 66 + r]      = v0 + b_def[r];
            lds[4096 + px * 66 + 32 + r] = v1 + b_def[32 + r];
        }
    }
    __syncthreads();
    float* op = out + (size_t)n * (OUTC * HWSZ) + h * 128 + w0;
#pragma unroll
    for (int i = 0; i < 8; ++i) {
        int idx = i * 256 + t;
        int o = idx >> 5, px = idx & 31;
        op[(size_t)o * HWSZ + px] = lds[4096 + px * 66 + o];
    }
}

extern "C" void kernel_launch(void* const* d_in, const int* in_sizes, int n_in,
                              void* d_out, int out_size, void* d_ws, size_t ws_size,
                              hipStream_t stream) {
    const float* x     = (const float*)d_in[0];
    const float* w_off = (const float*)d_in[1];
    const float* b_off = (const float*)d_in[2];
    const float* w_def = (const float*)d_in[3];
    const float* b_def = (const float*)d_in[4];
    float* ws   = (float*)d_ws;
    float* outp = (float*)d_out;

    // ws: wofT[0,16384) | wB 73728 ushort = [16384,53248) | xT | off20
    float* wofT  = ws;
    unsigned short* wB = (unsigned short*)(ws + 16384);
    float* xT    = ws + 53248;
    float* off20 = xT + 4194304;

    prep_kernel<<<288, 256, 0, stream>>>(w_off, w_def, ws);
    xpose_kernel<<<512, 256, 0, stream>>>(x, xT);
    offconv2_kernel<<<1024, 256, 0, stream>>>(xT, wofT, b_off, off20);
    deform_mfma4_kernel<<<2048, 256, 0, stream>>>(xT, off20, wB, b_def, outp);
}